// Round 11
// baseline (5767.638 us; speedup 1.0000x reference)
//
#include <hip/hip_runtime.h>

// B=256, T=512, I=128, H=256, 4H=1024
// 64 blocks = 4 row-groups x 16 col-groups. r4 protocol (untagged packed h; drain ->
// flag -> poll; all cross-block ops device-scope sc0 sc1) with three surgical fixes:
//  (1) per-WAVE flag chains (16 independent chains; no in-loop __syncthreads)
//  (2) x->bf16 conversion pinned BEFORE h-load issue so the compiler's x-wait is free
//      and x-MFMA truly overlaps h-load flight
//  (3) decoder out-stores after the flag post (drained during next poll's slack)

typedef __bf16 bf16;
typedef bf16 bf16x8 __attribute__((ext_vector_type(8)));
typedef float f32x4 __attribute__((ext_vector_type(4)));
typedef unsigned u32;
typedef u32 u32x4 __attribute__((ext_vector_type(4)));

#define MFMA16(a, b, c) __builtin_amdgcn_mfma_f32_16x16x32_bf16((a), (b), (c), 0, 0, 0)
#define AT_STORE_DEV(p, v) __hip_atomic_store((p), (v), __ATOMIC_RELAXED, __HIP_MEMORY_SCOPE_AGENT)

__device__ __forceinline__ float sigm(float x) { return 1.0f / (1.0f + __expf(-x)); }
__device__ __forceinline__ float tanhfast(float x) { return 1.0f - 2.0f / (__expf(2.0f * x) + 1.0f); }

// device-coherent ops (L1+L2 bypass) — r4-proven paths
__device__ __forceinline__ u32x4 load_hx4(const u32* p) {
    u32x4 v;
    asm volatile("global_load_dwordx4 %0, %1, off sc0 sc1" : "=v"(v) : "v"(p));
    return v;
}
__device__ __forceinline__ void store_h(u32* p, u32 v) {
    asm volatile("global_store_dword %0, %1, off sc0 sc1" :: "v"(p), "v"(v) : "memory");
}
__device__ __forceinline__ u32 load_flag(const u32* p) {
    u32 v;
    asm volatile("global_load_dword %0, %1, off sc0 sc1\n\ts_waitcnt vmcnt(0)"
                 : "=v"(v) : "v"(p) : "memory");
    return v;
}
#define DRAIN0() do { asm volatile("s_waitcnt vmcnt(0)" ::: "memory"); \
                      __builtin_amdgcn_sched_barrier(0); } while (0)

// ---------------- weight packing (fragment layout, unchanged) ----------------
__global__ void pack_kernel(const float* __restrict__ eWih, const float* __restrict__ eWhh,
                            const float* __restrict__ dWih, const float* __restrict__ dWhh,
                            const float* __restrict__ linW,
                            bf16* __restrict__ encB, bf16* __restrict__ decB, bf16* __restrict__ linB) {
    int idx = blockIdx.x * 256 + threadIdx.x;  // 0 .. 819199
    if (idx < 786432) {
        int which = idx / 393216;          // 0 = enc, 1 = dec
        int id = idx % 393216;
        int cg = id / 24576;
        int rem = id % 24576;
        int ks = rem / 2048;
        int n = (rem / 512) & 3;
        int lane = (rem >> 3) & 63;
        int e = rem & 7;
        int k = ks * 32 + (lane >> 4) * 8 + e;
        int col = n * 256 + cg * 16 + (lane & 15);
        const float* Wih = which ? dWih : eWih;
        const float* Whh = which ? dWhh : eWhh;
        float v = (k < 128) ? Wih[col * 128 + k] : Whh[col * 256 + (k - 128)];
        (which ? decB : encB)[id] = (bf16)v;
    } else if (idx < 819200) {
        int i3 = idx - 786432;             // 0 .. 32767
        int ks = i3 >> 12;
        int n = (i3 >> 9) & 7;
        int lane = (i3 >> 3) & 63;
        int e = i3 & 7;
        int k = ks * 32 + (lane >> 4) * 8 + e;
        int col = n * 16 + (lane & 15);
        linB[i3] = (bf16)linW[col * 256 + k];
    }
}

__global__ void zero_kernel(unsigned* __restrict__ p) {
    int i = blockIdx.x * 256 + threadIdx.x;
    // h ping-pong (65536 words) + per-wave flags (256 words)
    if (i < 65792) AT_STORE_DEV(&p[i], 0u);
}

// ---------------- main persistent kernel ----------------
__global__ __launch_bounds__(256, 1)
void lstm_main(const float* __restrict__ x,
               const float* __restrict__ eb_ih, const float* __restrict__ eb_hh,
               const float* __restrict__ db_ih, const float* __restrict__ db_hh,
               const float* __restrict__ lin_b,
               const bf16* __restrict__ encB, const bf16* __restrict__ decB,
               const bf16* __restrict__ linB,
               u32* __restrict__ hbuf32, u32* __restrict__ flags,
               float* __restrict__ out) {
    __shared__ bf16 Bg[24576];         // 48 KB gate-weight fragments (this cg)
    __shared__ bf16 Lw[32768];         // 64 KB lin_W fragments (decoder)
    __shared__ bf16 Pst[4 * 16 * 136]; // 17 KB pred staging, per-wave, pitch 136

    const int bid = blockIdx.x;
    const int rg = bid >> 4;           // row-group 0..3  (64 batch rows)
    const int cg = bid & 15;           // col-group 0..15 (16 hidden units)
    const int tid = threadIdx.x;
    const int w = tid >> 6;
    const int lane = tid & 63;
    const int l15 = lane & 15, l4 = lane >> 4;
    const int rbase = rg * 64 + w * 16;       // wave's 16 batch rows
    const int ucol = cg * 16 + l15;           // this lane's hidden unit
    const int arow = rbase + l15;             // A-fragment row this lane loads
    const int k0 = l4 * 8;                    // A-fragment k sub-offset
    const int prow = rbase + l4 * 4;          // epilogue row base

    // h fragment layout: hbuf[phase][rt=16][ks=8][256 words]  (r4-proven)
    const int rt = rg * 4 + w;                // this wave's row tile (reads & writes)
    const int htile_w = (cg >> 1) * 256;      // writer's ks-tile
    const int hgrp = ((cg & 1) * 2 + (l15 >> 3)) * 16;
    const int widx = (l15 & 7) >> 1;

    // per-wave flag chain: one 64 B line of 16 words per rt
    u32* myflag = flags + rt * 16 + cg;
    const u32* pollp = flags + rt * 16 + l15;

    // load encoder gate weights into LDS
    {
        const f32x4* src = (const f32x4*)(encB + cg * 24576);
        f32x4* dst = (f32x4*)Bg;
        #pragma unroll
        for (int i = 0; i < 12; i++) dst[tid + 256 * i] = src[tid + 256 * i];
    }
    float bias_g[4];
    #pragma unroll
    for (int g = 0; g < 4; g++) bias_g[g] = eb_ih[g * 256 + ucol] + eb_hh[g * 256 + ucol];
    __syncthreads();

    float c[4] = {0.f, 0.f, 0.f, 0.f};
    const float* xrow = x + (size_t)arow * 512 * 128 + k0;  // x[arow][t][k0+..]

    // preload x fragments for t=0
    f32x4 xr[8];
    #pragma unroll
    for (int i = 0; i < 4; i++) {
        xr[2 * i]     = *(const f32x4*)(xrow + i * 32);
        xr[2 * i + 1] = *(const f32x4*)(xrow + i * 32 + 4);
    }

    // =================== encoder: 512 steps ===================
    for (int t = 0; t < 512; t++) {
        const u32* hr32 = hbuf32 + (t & 1) * 32768;
        u32* hw32 = hbuf32 + ((t + 1) & 1) * 32768;

        // (2) convert x fragments FIRST: compiler's x-load wait lands here, where it is
        // free (previous poll's vmcnt(0) drained them). Fence so nothing sinks below.
        bf16x8 abf[4];
        #pragma unroll
        for (int ks = 0; ks < 4; ks++) {
            f32x4 xa = xr[2 * ks], xb = xr[2 * ks + 1];
            bf16x8 a;
            a[0] = (bf16)xa[0]; a[1] = (bf16)xa[1]; a[2] = (bf16)xa[2]; a[3] = (bf16)xa[3];
            a[4] = (bf16)xb[0]; a[5] = (bf16)xb[1]; a[6] = (bf16)xb[2]; a[7] = (bf16)xb[3];
            abf[ks] = a;
        }
        __builtin_amdgcn_sched_barrier(0);

        // issue 8 coalesced h-tile loads (now the only outstanding VMEM)
        u32x4 hv[8];
        const u32* hb = hr32 + rt * 2048 + lane * 4;
        #pragma unroll
        for (int ks = 0; ks < 8; ks++) hv[ks] = load_hx4(hb + ks * 256);

        f32x4 acc[4];
        #pragma unroll
        for (int n = 0; n < 4; n++) acc[n] = (f32x4){0.f, 0.f, 0.f, 0.f};

        // x part (K 0..127) — genuinely overlaps h-load flight
        #pragma unroll
        for (int ks = 0; ks < 4; ks++) {
            #pragma unroll
            for (int n = 0; n < 4; n++) {
                bf16x8 b = *(const bf16x8*)&Bg[((ks * 4 + n) * 64 + lane) * 8];
                acc[n] = MFMA16(abf[ks], b, acc[n]);
            }
        }
        DRAIN0();                      // h fragments resident

        // h part (K 128..383)
        #pragma unroll
        for (int ks = 0; ks < 8; ks++) {
            bf16x8 a = __builtin_bit_cast(bf16x8, hv[ks]);
            #pragma unroll
            for (int n = 0; n < 4; n++) {
                bf16x8 b = *(const bf16x8*)&Bg[(((ks + 4) * 4 + n) * 64 + lane) * 8];
                acc[n] = MFMA16(a, b, acc[n]);
            }
        }
        // epilogue: lane owns rows prow+r, unit ucol; packed fragment-layout h stores
        #pragma unroll
        for (int r = 0; r < 4; r++) {
            float gi = sigm(acc[0][r] + bias_g[0]);
            float gf = sigm(acc[1][r] + bias_g[1]);
            float gg = tanhfast(acc[2][r] + bias_g[2]);
            float go = sigm(acc[3][r] + bias_g[3]);
            c[r] = gf * c[r] + gi * gg;
            float h = go * tanhfast(c[r]);
            unsigned hvv = (unsigned)__builtin_bit_cast(unsigned short, (bf16)h);
            unsigned hp = __shfl_xor(hvv, 1);
            if (!(lane & 1))
                store_h(&hw32[rt * 2048 + htile_w + (hgrp + l4 * 4 + r) * 4 + widx],
                        hvv | (hp << 16));
        }
        // (1) per-wave barrier: drain own h stores -> post own flag
        DRAIN0();
        if (lane == 0) store_h(myflag, (u32)(t + 1));
        // x prefetch for t+1 (r4 placement: after flag; drained during poll slack)
        int tn = t < 511 ? t + 1 : 511;
        #pragma unroll
        for (int i = 0; i < 4; i++) {
            xr[2 * i]     = *(const f32x4*)(xrow + (size_t)tn * 128 + i * 32);
            xr[2 * i + 1] = *(const f32x4*)(xrow + (size_t)tn * 128 + i * 32 + 4);
        }
        // wide poll: all 16 same-rt writers posted step t+1
        {
            int sp = 0;
            while (!__all((int)(load_flag(pollp) >= (u32)(t + 1)))) {
                if (++sp > 16384) break;   // fail-fast, never a timeout
                __builtin_amdgcn_s_sleep(1);
            }
        }
        __builtin_amdgcn_sched_barrier(0);
    }

    // =================== switch to decoder weights ===================
    __syncthreads();   // all 4 waves of this block passed their t=511 poll -> Bg free
    {
        const f32x4* src = (const f32x4*)(decB + cg * 24576);
        f32x4* dst = (f32x4*)Bg;
        #pragma unroll
        for (int i = 0; i < 12; i++) dst[tid + 256 * i] = src[tid + 256 * i];
        const f32x4* s2 = (const f32x4*)linB;
        f32x4* d2 = (f32x4*)Lw;
        #pragma unroll
        for (int i = 0; i < 16; i++) d2[tid + 256 * i] = s2[tid + 256 * i];
    }
    float bias_d[4];
    #pragma unroll
    for (int g = 0; g < 4; g++) bias_d[g] = db_ih[g * 256 + ucol] + db_hh[g * 256 + ucol];
    float lbias[8];
    #pragma unroll
    for (int n = 0; n < 8; n++) lbias[n] = lin_b[n * 16 + l15];
    __syncthreads();

    const int ncg = cg >> 1;   // out columns this block writes: n == ncg, half == (cg&1)
    const int hsel = cg & 1;

    // =================== decoder: pred(k) then gates(k) ===================
    for (int k = 0; k < 512; k++) {
        const u32* hr32 = hbuf32 + (k & 1) * 32768;
        const u32 stepv = (u32)(512 + k);

        u32x4 hv[8];
        const u32* hb = hr32 + rt * 2048 + lane * 4;
        #pragma unroll
        for (int ks = 0; ks < 8; ks++) hv[ks] = load_hx4(hb + ks * 256);
        DRAIN0();
        bf16x8 ha[8];
        #pragma unroll
        for (int ks = 0; ks < 8; ks++) ha[ks] = __builtin_bit_cast(bf16x8, hv[ks]);

        // pred = sigmoid(h @ lin_W^T + lin_b)  [64 x 128], redundant per block
        f32x4 pacc[8];
        #pragma unroll
        for (int n = 0; n < 8; n++) pacc[n] = (f32x4){0.f, 0.f, 0.f, 0.f};
        #pragma unroll
        for (int ks = 0; ks < 8; ks++) {
            #pragma unroll
            for (int n = 0; n < 8; n++) {
                bf16x8 b = *(const bf16x8*)&Lw[((ks * 8 + n) * 64 + lane) * 8];
                pacc[n] = MFMA16(ha[ks], b, pacc[n]);
            }
        }
        const int t_out = 511 - k;
        float* obase = out + (size_t)prow * 512 * 128 + (size_t)t_out * 128;
        bf16* pst_w = Pst + w * 2176;
        #pragma unroll
        for (int n = 0; n < 8; n++) {
            #pragma unroll
            for (int r = 0; r < 4; r++) {
                float p = sigm(pacc[n][r] + lbias[n]);
                pst_w[(l4 * 4 + r) * 136 + n * 16 + l15] = (bf16)p;
            }
        }
        if (k == 511) {   // last step: prediction only
            #pragma unroll
            for (int r = 0; r < 4; r++) {
                float p = sigm(pacc[ncg][r] + lbias[ncg]);
                if ((l15 >> 3) == hsel)
                    obase[(size_t)r * 512 * 128 + ncg * 16 + l15] = p;
            }
            break;
        }

        // gates = [pred | h] @ Wdec^T : h-part, then pred-part from Pst (same wave)
        f32x4 acc[4];
        #pragma unroll
        for (int n = 0; n < 4; n++) acc[n] = (f32x4){0.f, 0.f, 0.f, 0.f};
        #pragma unroll
        for (int ks = 0; ks < 8; ks++) {
            #pragma unroll
            for (int n = 0; n < 4; n++) {
                bf16x8 b = *(const bf16x8*)&Bg[(((ks + 4) * 4 + n) * 64 + lane) * 8];
                acc[n] = MFMA16(ha[ks], b, acc[n]);
            }
        }
        const bf16* pst_r = Pst + w * 2176 + l15 * 136 + k0;
        #pragma unroll
        for (int ks = 0; ks < 4; ks++) {
            bf16x8 a = *(const bf16x8*)(pst_r + ks * 32);
            #pragma unroll
            for (int n = 0; n < 4; n++) {
                bf16x8 b = *(const bf16x8*)&Bg[((ks * 4 + n) * 64 + lane) * 8];
                acc[n] = MFMA16(a, b, acc[n]);
            }
        }
        // h epilogue -> drain own h stores -> flag -> (3) deferred out stores -> poll
        u32* hw32 = hbuf32 + ((k + 1) & 1) * 32768;
        #pragma unroll
        for (int r = 0; r < 4; r++) {
            float gi = sigm(acc[0][r] + bias_d[0]);
            float gf = sigm(acc[1][r] + bias_d[1]);
            float gg = tanhfast(acc[2][r] + bias_d[2]);
            float go = sigm(acc[3][r] + bias_d[3]);
            c[r] = gf * c[r] + gi * gg;
            float h = go * tanhfast(c[r]);
            unsigned hvv = (unsigned)__builtin_bit_cast(unsigned short, (bf16)h);
            unsigned hp = __shfl_xor(hvv, 1);
            if (!(lane & 1))
                store_h(&hw32[rt * 2048 + htile_w + (hgrp + l4 * 4 + r) * 4 + widx],
                        hvv | (hp << 16));
        }
        DRAIN0();
        if (lane == 0) store_h(myflag, stepv + 1u);
        #pragma unroll
        for (int r = 0; r < 4; r++) {
            float p = sigm(pacc[ncg][r] + lbias[ncg]);
            if ((l15 >> 3) == hsel)
                obase[(size_t)r * 512 * 128 + ncg * 16 + l15] = p;
        }
        {
            int sp = 0;
            while (!__all((int)(load_flag(pollp) >= stepv + 1u))) {
                if (++sp > 16384) break;
                __builtin_amdgcn_s_sleep(1);
            }
        }
        __builtin_amdgcn_sched_barrier(0);
    }
}

extern "C" void kernel_launch(void* const* d_in, const int* in_sizes, int n_in,
                              void* d_out, int out_size, void* d_ws, size_t ws_size,
                              hipStream_t stream) {
    const float* x    = (const float*)d_in[0];
    const float* eWih = (const float*)d_in[1];
    const float* eWhh = (const float*)d_in[2];
    const float* ebih = (const float*)d_in[3];
    const float* ebhh = (const float*)d_in[4];
    const float* dWih = (const float*)d_in[5];
    const float* dWhh = (const float*)d_in[6];
    const float* dbih = (const float*)d_in[7];
    const float* dbhh = (const float*)d_in[8];
    const float* linW = (const float*)d_in[9];
    const float* linb = (const float*)d_in[10];
    float* out = (float*)d_out;

    // workspace layout (~1.9 MB)
    bf16* encB = (bf16*)d_ws;            // 393216 bf16
    bf16* decB = encB + 393216;          // 393216 bf16
    bf16* linB = decB + 393216;          // 32768 bf16
    u32*  hbuf = (u32*)(linB + 32768);   // 2 x 16 tiles x 8 ks x 256 u32 (fragment layout)
    u32*  flags = hbuf + 65536;          // 16 rt-lines x 16 words

    hipLaunchKernelGGL(pack_kernel, dim3(3200), dim3(256), 0, stream,
                       eWih, eWhh, dWih, dWhh, linW, encB, decB, linB);
    hipLaunchKernelGGL(zero_kernel, dim3(257), dim3(256), 0, stream, hbuf);
    hipLaunchKernelGGL(lstm_main, dim3(64), dim3(256), 0, stream,
                       x, ebih, ebhh, dbih, dbhh, linb, encB, decB, linB, hbuf, flags, out);
}